// Round 7
// baseline (240.789 us; speedup 1.0000x reference)
//
#include <hip/hip_runtime.h>
#include <math.h>

#define GN 16
#define NCELL 4096
#define CAP 64

// ws layout (ints): hist[4096] @ 0, bucket[4096*CAP] @ 4096

__device__ __forceinline__ int cell_of(float x0, float x1, float x2) {
    int ix = (int)(x0 / 0.1875f + 8.0f); ix = ix < 0 ? 0 : (ix > 15 ? 15 : ix);
    int iy = (int)(x1 / 0.1875f + 8.0f); iy = iy < 0 ? 0 : (iy > 15 ? 15 : iy);
    int iz = (int)(x2 / 0.1875f + 8.0f); iz = iz < 0 ? 0 : (iz > 15 ? 15 : iz);
    return (ix * GN + iy) * GN + iz;
}

// emb layout: [v0,v1,v2, sin(2^0 v*), cos(2^0 v*), sin(2^1 v*), ...]
__device__ __forceinline__ float emb_val(int m, float v0, float v1, float v2) {
    if (m == 0) return v0;
    if (m == 1) return v1;
    if (m == 2) return v2;
    int t = m - 3, j = t / 6, rem = t - j * 6, comp = rem % 3;
    float v = (comp == 0) ? v0 : ((comp == 1) ? v1 : v2);
    float s = ldexpf(v, j);
    return (rem < 3) ? sinf(s) : cosf(s);
}

__global__ void k_zero(int* __restrict__ hist) {
    int t = blockIdx.x * blockDim.x + threadIdx.x;
    if (t < NCELL) hist[t] = 0;
}

__global__ void k_bin(const float* __restrict__ xg, float* __restrict__ out,
                      int* __restrict__ hist, int* __restrict__ bucket, int P) {
    int p = blockIdx.x * blockDim.x + threadIdx.x;
    if (p >= P) return;
    float x0 = xg[p*3+0], x1 = xg[p*3+1], x2 = xg[p*3+2];
    bool mask = (fabsf(x0) < 1.5f) && (fabsf(x1) < 1.5f) && (fabsf(x2) < 1.5f);
    if (mask) {
        int c = cell_of(x0, x1, x2);
        int slot = atomicAdd(&hist[c], 1);
        if (slot < CAP) bucket[c*CAP + slot] = p;
    } else {
        out[p*3+0] = 0.0f; out[p*3+1] = 0.0f; out[p*3+2] = 0.0f;
        out[(size_t)P*3 + p] = 0.0f;
    }
}

// One 1-wave (64-thread) block per cell. Stage all weights to LDS once,
// then 8 lanes/point x 8 points/pass, all weight reads LDS-broadcast b128.
__global__ __launch_bounds__(64, 4) void k_fwd(
    const float* __restrict__ xg, const float* __restrict__ dg,
    const float* __restrict__ l1w, const float* __restrict__ l1b,
    const float* __restrict__ l2w, const float* __restrict__ l2b,
    const float* __restrict__ l3w, const float* __restrict__ l3b,
    const float* __restrict__ l4w, const float* __restrict__ l4b,
    const float* __restrict__ l5w, const float* __restrict__ l5b,
    const int* __restrict__ hist, const int* __restrict__ bucket,
    float* __restrict__ out, int P)
{
    const int c = blockIdx.x;
    int n = hist[c];
    if (n <= 0) return;
    if (n > CAP) n = CAP;
    const int tid = threadIdx.x;
    const int g = tid >> 3;   // point slot in pass (0..7)
    const int k = tid & 7;    // lane in group; owns outputs 4k..4k+3

    __shared__ __align__(16) float sw1[2016];   // [63][32]
    __shared__ __align__(16) float sw2[1024];   // [32][32] (re-strided from 33)
    __shared__ __align__(16) float swd[32];     // w2 density column
    __shared__ __align__(16) float sw3[1024];   // [32][32]
    __shared__ __align__(16) float sw4[1888];   // [59][32]
    __shared__ __align__(16) float sw5[96];     // [32][3]
    __shared__ __align__(16) float sb1[32];
    __shared__ __align__(16) float sb2[36];     // 33 used
    __shared__ __align__(16) float sb3[32];
    __shared__ __align__(16) float sb4[32];
    __shared__ __align__(16) float sb5[4];      // 3 used
    __shared__ __align__(16) float s_emb[8][68]; // emb_x(63); stride 68
    __shared__ __align__(16) float s_cat[8][68]; // [h3(32)|emb_d(27)]
    __shared__ __align__(16) float s_act[8][36]; // 32-wide activations

    // ---- stage weights (coalesced float4 where aligned) ----
    {
        const float4* g1 = (const float4*)(l1w + (size_t)c*2016);
        for (int m = tid; m < 504; m += 64) ((float4*)sw1)[m] = g1[m];
        const float4* g3 = (const float4*)(l3w + (size_t)c*1024);
        for (int m = tid; m < 256; m += 64) ((float4*)sw3)[m] = g3[m];
        const float4* g4 = (const float4*)(l4w + (size_t)c*1888);
        for (int m = tid; m < 472; m += 64) ((float4*)sw4)[m] = g4[m];
        const float4* g5 = (const float4*)(l5w + (size_t)c*96);
        for (int m = tid; m < 24; m += 64) ((float4*)sw5)[m] = g5[m];
        // w2: stride 33 -> 32 + density column (scalar, coalesced global reads)
        const float* g2 = l2w + (size_t)c*1056;
        for (int f = tid; f < 1056; f += 64) {
            float v = g2[f];
            int r = f / 33, col = f - r*33;
            if (col < 32) sw2[r*32 + col] = v; else swd[r] = v;
        }
        if (tid < 8)  ((float4*)sb1)[tid] = ((const float4*)(l1b + (size_t)c*32))[tid];
        if (tid < 33) sb2[tid] = l2b[(size_t)c*33 + tid];
        if (tid >= 8 && tid < 16)  ((float4*)sb3)[tid-8]  = ((const float4*)(l3b + (size_t)c*32))[tid-8];
        if (tid >= 16 && tid < 24) ((float4*)sb4)[tid-16] = ((const float4*)(l4b + (size_t)c*32))[tid-16];
        if (tid >= 61) sb5[tid-61] = l5b[(size_t)c*3 + (tid-61)];
    }
    __syncthreads();

    for (int base = 0; base < n; base += 8) {
        const int idx = base + g;
        const bool live = idx < n;
        const int p = bucket[c*CAP + (live ? idx : (n-1))];

        const float x0 = xg[p*3+0], x1 = xg[p*3+1], x2 = xg[p*3+2];
        const float d0 = dg[p*3+0], d1 = dg[p*3+1], d2 = dg[p*3+2];

        for (int m = k; m < 63; m += 8) s_emb[g][m] = emb_val(m, x0, x1, x2);
        for (int m = k; m < 27; m += 8) s_cat[g][32+m] = emb_val(m, d0, d1, d2);
        __syncthreads();

        // ---- L1: 63 -> 32, relu ----
        float4 bb = *(const float4*)&sb1[4*k];
        float a0 = bb.x, a1 = bb.y, a2 = bb.z, a3 = bb.w;
        #pragma unroll 5
        for (int t = 0; t < 15; ++t) {
            const float4 av = *(const float4*)&s_emb[g][4*t];
            #pragma unroll
            for (int j = 0; j < 4; ++j) {
                const float aj = (&av.x)[j];
                const float4 wv = *(const float4*)&sw1[(4*t+j)*32 + 4*k];
                a0 = fmaf(aj, wv.x, a0); a1 = fmaf(aj, wv.y, a1);
                a2 = fmaf(aj, wv.z, a2); a3 = fmaf(aj, wv.w, a3);
            }
        }
        #pragma unroll
        for (int u = 60; u < 63; ++u) {
            const float aj = s_emb[g][u];
            const float4 wv = *(const float4*)&sw1[u*32 + 4*k];
            a0 = fmaf(aj, wv.x, a0); a1 = fmaf(aj, wv.y, a1);
            a2 = fmaf(aj, wv.z, a2); a3 = fmaf(aj, wv.w, a3);
        }
        const float h10 = fmaxf(a0,0.f), h11 = fmaxf(a1,0.f);
        const float h12 = fmaxf(a2,0.f), h13 = fmaxf(a3,0.f);

        // density = relu(h1 . w2[:,32] + b2[32])
        float dp = h10*swd[4*k+0] + h11*swd[4*k+1] + h12*swd[4*k+2] + h13*swd[4*k+3];
        dp += __shfl_xor(dp, 1, 8);
        dp += __shfl_xor(dp, 2, 8);
        dp += __shfl_xor(dp, 4, 8);
        const float density = fmaxf(dp + sb2[32], 0.f);

        *(float4*)&s_act[g][4*k] = make_float4(h10, h11, h12, h13);
        __syncthreads();

        // ---- L2: 32 -> 32, relu (re-strided, b128) ----
        a0 = sb2[4*k+0]; a1 = sb2[4*k+1]; a2 = sb2[4*k+2]; a3 = sb2[4*k+3];
        #pragma unroll 4
        for (int t = 0; t < 8; ++t) {
            const float4 av = *(const float4*)&s_act[g][4*t];
            #pragma unroll
            for (int j = 0; j < 4; ++j) {
                const float aj = (&av.x)[j];
                const float4 wv = *(const float4*)&sw2[(4*t+j)*32 + 4*k];
                a0 = fmaf(aj, wv.x, a0); a1 = fmaf(aj, wv.y, a1);
                a2 = fmaf(aj, wv.z, a2); a3 = fmaf(aj, wv.w, a3);
            }
        }
        const float h20 = fmaxf(a0,0.f), h21 = fmaxf(a1,0.f);
        const float h22 = fmaxf(a2,0.f), h23 = fmaxf(a3,0.f);
        __syncthreads();                 // all reads of s_act (h1) done
        *(float4*)&s_act[g][4*k] = make_float4(h20, h21, h22, h23);
        __syncthreads();

        // ---- L3: 32 -> 32, no activation ----
        bb = *(const float4*)&sb3[4*k];
        a0 = bb.x; a1 = bb.y; a2 = bb.z; a3 = bb.w;
        #pragma unroll 4
        for (int t = 0; t < 8; ++t) {
            const float4 av = *(const float4*)&s_act[g][4*t];
            #pragma unroll
            for (int j = 0; j < 4; ++j) {
                const float aj = (&av.x)[j];
                const float4 wv = *(const float4*)&sw3[(4*t+j)*32 + 4*k];
                a0 = fmaf(aj, wv.x, a0); a1 = fmaf(aj, wv.y, a1);
                a2 = fmaf(aj, wv.z, a2); a3 = fmaf(aj, wv.w, a3);
            }
        }
        *(float4*)&s_cat[g][4*k] = make_float4(a0, a1, a2, a3);   // h3
        __syncthreads();

        // ---- L4: [h3(32)|emb_d(27)] = 59 -> 32, relu ----
        bb = *(const float4*)&sb4[4*k];
        a0 = bb.x; a1 = bb.y; a2 = bb.z; a3 = bb.w;
        #pragma unroll 7
        for (int t = 0; t < 14; ++t) {
            const float4 av = *(const float4*)&s_cat[g][4*t];
            #pragma unroll
            for (int j = 0; j < 4; ++j) {
                const float aj = (&av.x)[j];
                const float4 wv = *(const float4*)&sw4[(4*t+j)*32 + 4*k];
                a0 = fmaf(aj, wv.x, a0); a1 = fmaf(aj, wv.y, a1);
                a2 = fmaf(aj, wv.z, a2); a3 = fmaf(aj, wv.w, a3);
            }
        }
        #pragma unroll
        for (int u = 56; u < 59; ++u) {
            const float aj = s_cat[g][u];
            const float4 wv = *(const float4*)&sw4[u*32 + 4*k];
            a0 = fmaf(aj, wv.x, a0); a1 = fmaf(aj, wv.y, a1);
            a2 = fmaf(aj, wv.z, a2); a3 = fmaf(aj, wv.w, a3);
        }
        const float h40 = fmaxf(a0,0.f), h41 = fmaxf(a1,0.f);
        const float h42 = fmaxf(a2,0.f), h43 = fmaxf(a3,0.f);

        // ---- L5: 32 -> 3, sigmoid ----
        float c0 = h40*sw5[(4*k+0)*3+0] + h41*sw5[(4*k+1)*3+0]
                 + h42*sw5[(4*k+2)*3+0] + h43*sw5[(4*k+3)*3+0];
        float c1 = h40*sw5[(4*k+0)*3+1] + h41*sw5[(4*k+1)*3+1]
                 + h42*sw5[(4*k+2)*3+1] + h43*sw5[(4*k+3)*3+1];
        float c2 = h40*sw5[(4*k+0)*3+2] + h41*sw5[(4*k+1)*3+2]
                 + h42*sw5[(4*k+2)*3+2] + h43*sw5[(4*k+3)*3+2];
        #pragma unroll
        for (int m = 1; m <= 4; m <<= 1) {
            c0 += __shfl_xor(c0, m, 8);
            c1 += __shfl_xor(c1, m, 8);
            c2 += __shfl_xor(c2, m, 8);
        }

        if (live && k == 0) {
            out[p*3+0] = 1.0f / (1.0f + expf(-(c0 + sb5[0])));
            out[p*3+1] = 1.0f / (1.0f + expf(-(c1 + sb5[1])));
            out[p*3+2] = 1.0f / (1.0f + expf(-(c2 + sb5[2])));
            out[(size_t)P*3 + p] = density;
        }
        __syncthreads();   // protect LDS before next pass
    }
}

extern "C" void kernel_launch(void* const* d_in, const int* in_sizes, int n_in,
                              void* d_out, int out_size, void* d_ws, size_t ws_size,
                              hipStream_t stream) {
    const float* x   = (const float*)d_in[0];
    const float* d   = (const float*)d_in[1];
    const float* l1w = (const float*)d_in[2];
    const float* l1b = (const float*)d_in[3];
    const float* l2w = (const float*)d_in[4];
    const float* l2b = (const float*)d_in[5];
    const float* l3w = (const float*)d_in[6];
    const float* l3b = (const float*)d_in[7];
    const float* l4w = (const float*)d_in[8];
    const float* l4b = (const float*)d_in[9];
    const float* l5w = (const float*)d_in[10];
    const float* l5b = (const float*)d_in[11];
    float* out = (float*)d_out;

    const int P = in_sizes[0] / 3;   // 32768
    int* ws = (int*)d_ws;
    int* hist   = ws;
    int* bucket = ws + NCELL;

    k_zero<<<(NCELL + 255)/256, 256, 0, stream>>>(hist);
    k_bin<<<(P + 255)/256, 256, 0, stream>>>(x, out, hist, bucket, P);
    k_fwd<<<NCELL, 64, 0, stream>>>(x, d, l1w, l1b, l2w, l2b, l3w, l3b,
                                    l4w, l4b, l5w, l5b, hist, bucket, out, P);
}

// Round 10
// 200.997 us; speedup vs baseline: 1.1980x; 1.1980x over previous
//
#include <hip/hip_runtime.h>
#include <math.h>

#define GN 16
#define NCELL 4096

// ws layout (ints): cell[P] @0, order[P] @P, hist @2P, offs @2P+4096,
//                   cursor @2P+8192, total @2P+12288

__device__ __forceinline__ int cell_of(float x0, float x1, float x2) {
    int ix = (int)(x0 / 0.1875f + 8.0f); ix = ix < 0 ? 0 : (ix > 15 ? 15 : ix);
    int iy = (int)(x1 / 0.1875f + 8.0f); iy = iy < 0 ? 0 : (iy > 15 ? 15 : iy);
    int iz = (int)(x2 / 0.1875f + 8.0f); iz = iz < 0 ? 0 : (iz > 15 ? 15 : iz);
    return (ix * GN + iy) * GN + iz;
}

// emb layout: [v0,v1,v2, sin(2^0 v*), cos(2^0 v*), sin(2^1 v*), ...]
__device__ __forceinline__ float emb_val(int m, float v0, float v1, float v2) {
    if (m == 0) return v0;
    if (m == 1) return v1;
    if (m == 2) return v2;
    int t = m - 3, j = t / 6, rem = t - j * 6, comp = rem % 3;
    float v = (comp == 0) ? v0 : ((comp == 1) ? v1 : v2);
    float s = ldexpf(v, j);
    return (rem < 3) ? sinf(s) : cosf(s);
}

__global__ void k_zero(int* __restrict__ hist) {
    int t = blockIdx.x * blockDim.x + threadIdx.x;
    if (t < NCELL) hist[t] = 0;
}

__global__ void k_classify(const float* __restrict__ xg, float* __restrict__ out,
                           int* __restrict__ cell, int* __restrict__ hist, int P) {
    int p = blockIdx.x * blockDim.x + threadIdx.x;
    if (p >= P) return;
    float x0 = xg[p*3+0], x1 = xg[p*3+1], x2 = xg[p*3+2];
    bool mask = (fabsf(x0) < 1.5f) && (fabsf(x1) < 1.5f) && (fabsf(x2) < 1.5f);
    if (mask) {
        int c = cell_of(x0, x1, x2);
        cell[p] = c;
        atomicAdd(&hist[c], 1);
    } else {
        cell[p] = -1;
        out[p*3+0] = 0.0f; out[p*3+1] = 0.0f; out[p*3+2] = 0.0f;
        out[(size_t)P*3 + p] = 0.0f;
    }
}

__global__ __launch_bounds__(1024) void k_scan(const int* __restrict__ hist,
                                               int* __restrict__ offs,
                                               int* __restrict__ cursor,
                                               int* __restrict__ total) {
    __shared__ int s[1024];
    const int t = threadIdx.x;
    const int base = t * 4;
    int a0 = hist[base+0], a1 = hist[base+1], a2 = hist[base+2], a3 = hist[base+3];
    int sum = a0 + a1 + a2 + a3;
    s[t] = sum;
    __syncthreads();
    #pragma unroll
    for (int off = 1; off < 1024; off <<= 1) {
        int v = (t >= off) ? s[t - off] : 0;
        __syncthreads();
        s[t] += v;
        __syncthreads();
    }
    int excl = s[t] - sum;
    int e0 = excl, e1 = e0 + a0, e2 = e1 + a1, e3 = e2 + a2;
    offs[base+0] = e0; offs[base+1] = e1; offs[base+2] = e2; offs[base+3] = e3;
    cursor[base+0] = e0; cursor[base+1] = e1; cursor[base+2] = e2; cursor[base+3] = e3;
    if (t == 1023) *total = s[1023];
}

__global__ void k_scatter(const int* __restrict__ cell, int* __restrict__ cursor,
                          int* __restrict__ order, int P) {
    int p = blockIdx.x * blockDim.x + threadIdx.x;
    if (p >= P) return;
    int c = cell[p];
    if (c >= 0) {
        int pos = atomicAdd(&cursor[c], 1);
        order[pos] = p;
    }
}

// 256 threads = 4 waves = 8 points. 32 lanes per point:
//   grp = (lane&31)>>3 selects input row r = 4t+grp (K split 4 ways),
//   k   = lane&7 owns outputs 4k..4k+3 (float4 weight loads, 4 acc chains).
// LDS phases separated by __syncthreads (cross-lane LDS RAW/WAR needs a fence:
// compiler orders DS ops per-thread only). Buffer rotation so each store hits a
// buffer whose readers finished >=1 barrier earlier:
//   emb->s_emb,s_cat ; h1->s_act ; h2->s_emb[0..31] ; h3->s_cat[0..31] ; h4->s_act
__global__ __launch_bounds__(256, 8) void k_fwd(
    const float* __restrict__ xg, const float* __restrict__ dg,
    const float* __restrict__ l1w, const float* __restrict__ l1b,
    const float* __restrict__ l2w, const float* __restrict__ l2b,
    const float* __restrict__ l3w, const float* __restrict__ l3b,
    const float* __restrict__ l4w, const float* __restrict__ l4b,
    const float* __restrict__ l5w, const float* __restrict__ l5b,
    const int* __restrict__ order, const int* __restrict__ cellArr,
    const int* __restrict__ total,
    float* __restrict__ out, int P)
{
    const int n = *total;
    if ((int)blockIdx.x * 8 >= n) return;
    const int tid  = threadIdx.x;
    const int wave = tid >> 6;
    const int lane = tid & 63;
    const int half = lane >> 5;
    const int l    = lane & 31;
    const int grp  = l >> 3;
    const int k    = l & 7;
    const int gp   = wave * 2 + half;     // LDS row (0..7)

    const int s = blockIdx.x * 8 + gp;
    const bool live = s < n;
    const int p = order[live ? s : 0];
    const int cell = cellArr[p];

    __shared__ float s_emb[8][68];   // emb_x(63), [63]=0; rows 0..31 reused for h2
    __shared__ float s_act[8][36];   // h1, later h4
    __shared__ float s_cat[8][68];   // [h3(32) | emb_d(27) | [59]=0]

    const float x0 = xg[p*3+0], x1 = xg[p*3+1], x2 = xg[p*3+2];
    const float d0 = dg[p*3+0], d1 = dg[p*3+1], d2 = dg[p*3+2];

    s_emb[gp][l] = emb_val(l, x0, x1, x2);
    s_emb[gp][l+32] = (l+32 < 63) ? emb_val(l+32, x0, x1, x2) : 0.0f;
    if (l < 28) s_cat[gp][32+l] = (l < 27) ? emb_val(l, d0, d1, d2) : 0.0f;
    __syncthreads();                                   // SYNC1

    const float* w1 = l1w + cell*2016;
    const float* w2 = l2w + cell*1056;
    const float* w3 = l3w + cell*1024;
    const float* w4 = l4w + cell*1888;
    const float* w5 = l5w + cell*96;

    // ---- L1: 63 -> 32, relu ----
    float a0 = 0.f, a1 = 0.f, a2 = 0.f, a3 = 0.f;
    #pragma unroll
    for (int t = 0; t < 16; ++t) {
        const int r = 4*t + grp;
        const float aj = s_emb[gp][r];            // 8 distinct banks -> conflict-free
        const int rc = r > 62 ? 62 : r;           // r==63: aj==0, clamp addr
        const float4 wv = *(const float4*)(w1 + rc*32 + 4*k);
        a0 = fmaf(aj, wv.x, a0); a1 = fmaf(aj, wv.y, a1);
        a2 = fmaf(aj, wv.z, a2); a3 = fmaf(aj, wv.w, a3);
    }
    a0 += __shfl_xor(a0, 8, 32); a0 += __shfl_xor(a0, 16, 32);
    a1 += __shfl_xor(a1, 8, 32); a1 += __shfl_xor(a1, 16, 32);
    a2 += __shfl_xor(a2, 8, 32); a2 += __shfl_xor(a2, 16, 32);
    a3 += __shfl_xor(a3, 8, 32); a3 += __shfl_xor(a3, 16, 32);
    if (grp == 0) {
        const float4 bv = *(const float4*)(l1b + cell*32 + 4*k);
        *(float4*)&s_act[gp][4*k] = make_float4(fmaxf(a0+bv.x,0.f), fmaxf(a1+bv.y,0.f),
                                                fmaxf(a2+bv.z,0.f), fmaxf(a3+bv.w,0.f));
    }
    __syncthreads();                                   // SYNC2

    // ---- density = relu(h1 . w2[:,32] + b2[32]) (row-per-lane) ----
    {
        const float hv = s_act[gp][l];
        float dpp = hv * w2[l*33 + 32];
        dpp += __shfl_xor(dpp, 1, 32); dpp += __shfl_xor(dpp, 2, 32);
        dpp += __shfl_xor(dpp, 4, 32); dpp += __shfl_xor(dpp, 8, 32);
        dpp += __shfl_xor(dpp, 16, 32);
        if (live && l == 0)
            out[(size_t)P*3 + p] = fmaxf(dpp + l2b[cell*33+32], 0.f);
    }

    // ---- L2: 32 -> 32, relu (stride-33 rows); h2 -> s_emb[0..31] ----
    a0 = 0.f; a1 = 0.f; a2 = 0.f; a3 = 0.f;
    #pragma unroll
    for (int t = 0; t < 8; ++t) {
        const int r = 4*t + grp;
        const float aj = s_act[gp][r];
        const float* wr = w2 + r*33 + 4*k;
        a0 = fmaf(aj, wr[0], a0); a1 = fmaf(aj, wr[1], a1);
        a2 = fmaf(aj, wr[2], a2); a3 = fmaf(aj, wr[3], a3);
    }
    a0 += __shfl_xor(a0, 8, 32); a0 += __shfl_xor(a0, 16, 32);
    a1 += __shfl_xor(a1, 8, 32); a1 += __shfl_xor(a1, 16, 32);
    a2 += __shfl_xor(a2, 8, 32); a2 += __shfl_xor(a2, 16, 32);
    a3 += __shfl_xor(a3, 8, 32); a3 += __shfl_xor(a3, 16, 32);
    if (grp == 0) {
        const float b0 = l2b[cell*33 + 4*k+0], b1f = l2b[cell*33 + 4*k+1];
        const float b2f = l2b[cell*33 + 4*k+2], b3f = l2b[cell*33 + 4*k+3];
        *(float4*)&s_emb[gp][4*k] = make_float4(fmaxf(a0+b0,0.f), fmaxf(a1+b1f,0.f),
                                                fmaxf(a2+b2f,0.f), fmaxf(a3+b3f,0.f));
    }
    __syncthreads();                                   // SYNC3

    // ---- L3: 32 -> 32, no activation; h3 -> s_cat[0..31] ----
    a0 = 0.f; a1 = 0.f; a2 = 0.f; a3 = 0.f;
    #pragma unroll
    for (int t = 0; t < 8; ++t) {
        const int r = 4*t + grp;
        const float aj = s_emb[gp][r];
        const float4 wv = *(const float4*)(w3 + r*32 + 4*k);
        a0 = fmaf(aj, wv.x, a0); a1 = fmaf(aj, wv.y, a1);
        a2 = fmaf(aj, wv.z, a2); a3 = fmaf(aj, wv.w, a3);
    }
    a0 += __shfl_xor(a0, 8, 32); a0 += __shfl_xor(a0, 16, 32);
    a1 += __shfl_xor(a1, 8, 32); a1 += __shfl_xor(a1, 16, 32);
    a2 += __shfl_xor(a2, 8, 32); a2 += __shfl_xor(a2, 16, 32);
    a3 += __shfl_xor(a3, 8, 32); a3 += __shfl_xor(a3, 16, 32);
    if (grp == 0) {
        const float4 bv = *(const float4*)(l3b + cell*32 + 4*k);
        *(float4*)&s_cat[gp][4*k] = make_float4(a0+bv.x, a1+bv.y, a2+bv.z, a3+bv.w);
    }
    __syncthreads();                                   // SYNC4

    // ---- L4: [h3(32)|emb_d(27)] = 59 -> 32, relu; h4 -> s_act ----
    a0 = 0.f; a1 = 0.f; a2 = 0.f; a3 = 0.f;
    #pragma unroll
    for (int t = 0; t < 15; ++t) {
        const int r = 4*t + grp;
        const float aj = s_cat[gp][r];            // r==59 -> 0
        const int rc = r > 58 ? 58 : r;
        const float4 wv = *(const float4*)(w4 + rc*32 + 4*k);
        a0 = fmaf(aj, wv.x, a0); a1 = fmaf(aj, wv.y, a1);
        a2 = fmaf(aj, wv.z, a2); a3 = fmaf(aj, wv.w, a3);
    }
    a0 += __shfl_xor(a0, 8, 32); a0 += __shfl_xor(a0, 16, 32);
    a1 += __shfl_xor(a1, 8, 32); a1 += __shfl_xor(a1, 16, 32);
    a2 += __shfl_xor(a2, 8, 32); a2 += __shfl_xor(a2, 16, 32);
    a3 += __shfl_xor(a3, 8, 32); a3 += __shfl_xor(a3, 16, 32);
    if (grp == 0) {
        const float4 bv = *(const float4*)(l4b + cell*32 + 4*k);
        *(float4*)&s_act[gp][4*k] = make_float4(fmaxf(a0+bv.x,0.f), fmaxf(a1+bv.y,0.f),
                                                fmaxf(a2+bv.z,0.f), fmaxf(a3+bv.w,0.f));
    }
    __syncthreads();                                   // SYNC5

    // ---- L5: 32 -> 3, sigmoid (row-per-lane + full 32-lane reduce) ----
    {
        const float hv = s_act[gp][l];
        float c0 = hv * w5[l*3+0];
        float c1 = hv * w5[l*3+1];
        float c2 = hv * w5[l*3+2];
        #pragma unroll
        for (int m = 1; m <= 16; m <<= 1) {
            c0 += __shfl_xor(c0, m, 32);
            c1 += __shfl_xor(c1, m, 32);
            c2 += __shfl_xor(c2, m, 32);
        }
        if (live && l == 0) {
            out[p*3+0] = 1.0f / (1.0f + expf(-(c0 + l5b[cell*3+0])));
            out[p*3+1] = 1.0f / (1.0f + expf(-(c1 + l5b[cell*3+1])));
            out[p*3+2] = 1.0f / (1.0f + expf(-(c2 + l5b[cell*3+2])));
        }
    }
}

extern "C" void kernel_launch(void* const* d_in, const int* in_sizes, int n_in,
                              void* d_out, int out_size, void* d_ws, size_t ws_size,
                              hipStream_t stream) {
    const float* x   = (const float*)d_in[0];
    const float* d   = (const float*)d_in[1];
    const float* l1w = (const float*)d_in[2];
    const float* l1b = (const float*)d_in[3];
    const float* l2w = (const float*)d_in[4];
    const float* l2b = (const float*)d_in[5];
    const float* l3w = (const float*)d_in[6];
    const float* l3b = (const float*)d_in[7];
    const float* l4w = (const float*)d_in[8];
    const float* l4b = (const float*)d_in[9];
    const float* l5w = (const float*)d_in[10];
    const float* l5b = (const float*)d_in[11];
    float* out = (float*)d_out;

    const int P = in_sizes[0] / 3;   // 32768
    int* ws = (int*)d_ws;
    int* cell   = ws;
    int* order  = ws + P;
    int* hist   = ws + 2*P;
    int* offs   = ws + 2*P + NCELL;
    int* cursor = ws + 2*P + 2*NCELL;
    int* total  = ws + 2*P + 3*NCELL;

    k_zero<<<(NCELL + 255)/256, 256, 0, stream>>>(hist);
    k_classify<<<(P + 255)/256, 256, 0, stream>>>(x, out, cell, hist, P);
    k_scan<<<1, 1024, 0, stream>>>(hist, offs, cursor, total);
    k_scatter<<<(P + 255)/256, 256, 0, stream>>>(cell, cursor, order, P);
    k_fwd<<<(P + 7)/8, 256, 0, stream>>>(x, d, l1w, l1b, l2w, l2b, l3w, l3b,
                                         l4w, l4b, l5w, l5b,
                                         order, cell, total, out, P);
}